// Round 1
// baseline (294.357 us; speedup 1.0000x reference)
//
#include <hip/hip_runtime.h>

#define BB 16
#define TT 256
#define NN 2048
#define CT 32            // t-extent covered per block (4 teams x 8)
#define TI 8             // t-iterations per thread
#define NSLICE 16        // per-point partial slices (contention = 128/16 = 8)
#define WSBASE 64        // scalar floats reserved at front of ws

// ws float layout:
//  [3*s + 0..2], s<16 : per-slice (recon, temporal, nvel) partials
//  [48] identity contrib sum   [49] num_visible
//  [WSBASE + (s*13 + k)*NN + n], s<16, k<13 : cnt, sp0..2, qp0..2, sg0..2, qg0..2

__device__ __forceinline__ float waveReduceSum(float v) {
#pragma unroll
  for (int o = 32; o > 0; o >>= 1) v += __shfl_down(v, o, 64);
  return v;
}

__global__ __launch_bounds__(256, 3) void stats_kernel(
    const float* __restrict__ pred, const float* __restrict__ gt,
    const float* __restrict__ vis, float* __restrict__ ws) {
  const int tid  = threadIdx.x;
  const int lane = tid & 63;
  const int team = tid >> 6;
  const int nb   = blockIdx.x * 256;       // block's first point
  const int n0   = nb + lane * 4;          // this thread's first point (of 4)
  const int b    = blockIdx.y;
  const int tf   = blockIdx.z * CT + team * TI;

  const size_t rowe = (size_t)NN * 3;      // pred/gt elements per frame
  const float* __restrict__ pbase = pred + ((size_t)(b * TT + tf) * NN + n0) * 3;
  const float* __restrict__ gbase = gt   + ((size_t)(b * TT + tf) * NN + n0) * 3;
  const float* __restrict__ vbase = vis  + (size_t)(b * TT + tf) * NN + n0;

  float acc[4][13];
#pragma unroll
  for (int j = 0; j < 4; ++j)
#pragma unroll
    for (int k = 0; k < 13; ++k) acc[j][k] = 0.f;
  float pv[4][3], gv[4][3], mp[4];
  float recon = 0.f, temporal = 0.f, nvel = 0.f;

  // boundary frame tf-1 (velocity state only); tf==0 loads frame 0 with mask 0
  {
    const long off  = (tf == 0) ? 0 : -(long)rowe;
    const long voff = (tf == 0) ? 0 : -(long)NN;
    float4 A = *(const float4*)(pbase + off);
    float4 Bv = *(const float4*)(pbase + off + 4);
    float4 Cv = *(const float4*)(pbase + off + 8);
    float4 D = *(const float4*)(gbase + off);
    float4 E = *(const float4*)(gbase + off + 4);
    float4 F = *(const float4*)(gbase + off + 8);
    float4 V = *(const float4*)(vbase + voff);
    float ap[12] = {A.x,A.y,A.z,A.w,Bv.x,Bv.y,Bv.z,Bv.w,Cv.x,Cv.y,Cv.z,Cv.w};
    float ag[12] = {D.x,D.y,D.z,D.w,E.x,E.y,E.z,E.w,F.x,F.y,F.z,F.w};
    float av[4]  = {V.x,V.y,V.z,V.w};
#pragma unroll
    for (int j = 0; j < 4; ++j) {
      pv[j][0] = ap[3*j]; pv[j][1] = ap[3*j+1]; pv[j][2] = ap[3*j+2];
      gv[j][0] = ag[3*j]; gv[j][1] = ag[3*j+1]; gv[j][2] = ag[3*j+2];
      mp[j] = (tf != 0 && av[j] > 0.5f) ? 1.f : 0.f;
    }
  }

#pragma unroll
  for (int i = 0; i < TI; ++i) {
    const float* p = pbase + (size_t)i * rowe;
    const float* g = gbase + (size_t)i * rowe;
    const float* v = vbase + (size_t)i * NN;
    float4 A = *(const float4*)(p);
    float4 Bv = *(const float4*)(p + 4);
    float4 Cv = *(const float4*)(p + 8);
    float4 D = *(const float4*)(g);
    float4 E = *(const float4*)(g + 4);
    float4 F = *(const float4*)(g + 8);
    float4 V = *(const float4*)(v);
    float ap[12] = {A.x,A.y,A.z,A.w,Bv.x,Bv.y,Bv.z,Bv.w,Cv.x,Cv.y,Cv.z,Cv.w};
    float ag[12] = {D.x,D.y,D.z,D.w,E.x,E.y,E.z,E.w,F.x,F.y,F.z,F.w};
    float av[4]  = {V.x,V.y,V.z,V.w};

#pragma unroll
    for (int j = 0; j < 4; ++j) {
      float x  = ap[3*j], y  = ap[3*j+1], z  = ap[3*j+2];
      float gx = ag[3*j], gy = ag[3*j+1], gz = ag[3*j+2];
      float m = (av[j] > 0.5f) ? 1.f : 0.f;
      acc[j][0]  += m;
      acc[j][1]  += m * x;      acc[j][2]  += m * y;      acc[j][3]  += m * z;
      acc[j][4]  += m * x * x;  acc[j][5]  += m * y * y;  acc[j][6]  += m * z * z;
      acc[j][7]  += m * gx;     acc[j][8]  += m * gy;     acc[j][9]  += m * gz;
      acc[j][10] += m * gx * gx; acc[j][11] += m * gy * gy; acc[j][12] += m * gz * gz;
      float d0 = x - gx, d1 = y - gy, d2 = z - gz;
      recon += m * (d0 * d0 + d1 * d1 + 2.f * d2 * d2);
      float mv = m * mp[j];
      float vx = (x - pv[j][0]) - (gx - gv[j][0]);
      float vy = (y - pv[j][1]) - (gy - gv[j][1]);
      float vz = (z - pv[j][2]) - (gz - gv[j][2]);
      temporal += mv * (vx * vx + vy * vy + vz * vz);
      nvel += mv;
      pv[j][0] = x;  pv[j][1] = y;  pv[j][2] = z;
      gv[j][0] = gx; gv[j][1] = gy; gv[j][2] = gz;
      mp[j] = m;
    }
  }

  // ---- team merge in LDS, swizzled so ds_add is bank-conflict-free ----
  // point p (0..255) stored at column swz(p) = (p>>2) | ((p&3)<<6)
  __shared__ float lacc[13][256];
#pragma unroll
  for (int k = 0; k < 13; ++k) lacc[k][tid] = 0.f;
  __syncthreads();
#pragma unroll
  for (int j = 0; j < 4; ++j) {
    const int col = lane | (j << 6);   // swz(4*lane + j): stride-1 across lanes
#pragma unroll
    for (int k = 0; k < 13; ++k) atomicAdd(&lacc[k][col], acc[j][k]);
  }
  __syncthreads();

  const int slice = (b + 2 * blockIdx.z) & (NSLICE - 1);
  float* pts = ws + WSBASE + (size_t)slice * 13 * NN;
  const int swz = (tid >> 2) | ((tid & 3) << 6);
#pragma unroll
  for (int k = 0; k < 13; ++k)
    atomicAdd(&pts[(size_t)k * NN + nb + tid], lacc[k][swz]);

  // ---- scalar partials: block reduce, then one sliced atomic per scalar ----
  __shared__ float sred[3][4];
  float r0 = waveReduceSum(recon);
  float r1 = waveReduceSum(temporal);
  float r2 = waveReduceSum(nvel);
  if (lane == 0) { sred[0][team] = r0; sred[1][team] = r1; sred[2][team] = r2; }
  __syncthreads();
  if (tid < 3) {
    float s = sred[tid][0] + sred[tid][1] + sred[tid][2] + sred[tid][3];
    atomicAdd(&ws[slice * 3 + tid], s);
  }
}

__global__ __launch_bounds__(256) void identity_kernel(float* __restrict__ ws) {
  const int n = blockIdx.x * 256 + threadIdx.x;
  const float* base = ws + WSBASE;
  float st[13];
#pragma unroll
  for (int k = 0; k < 13; ++k) st[k] = 0.f;
#pragma unroll
  for (int s = 0; s < NSLICE; ++s) {
#pragma unroll
    for (int k = 0; k < 13; ++k) st[k] += base[(size_t)(s * 13 + k) * NN + n];
  }
  float c = st[0];
  float sp0 = st[1], sp1 = st[2], sp2 = st[3];
  float qp0 = st[4], qp1 = st[5], qp2 = st[6];
  float sg0 = st[7], sg1 = st[8], sg2 = st[9];
  float qg0 = st[10], qg1 = st[11], qg2 = st[12];

  float inv = 1.f / fmaxf(c, 1.f);
  float dv  = 1.f / fmaxf(c - 1.f, 1.f);
  float pv0 = (qp0 - sp0 * sp0 * inv) * dv;
  float pv1 = (qp1 - sp1 * sp1 * inv) * dv;
  float pv2 = (qp2 - sp2 * sp2 * inv) * dv;
  float gv0 = (qg0 - sg0 * sg0 * inv) * dv;
  float gv1 = (qg1 - sg1 * sg1 * inv) * dv;
  float gv2 = (qg2 - sg2 * sg2 * inv) * dv;

  float num = fabsf(pv0 - gv0) + fabsf(pv1 - gv1) + fabsf(pv2 - gv2);
  float den = gv0 + gv1 + gv2 + 1e-6f;
  float contrib = (c > 1.f) ? (num / den) : 0.f;

  __shared__ float sred[2][4];
  float r0 = waveReduceSum(contrib);
  float r1 = waveReduceSum(c);
  int lane = threadIdx.x & 63, w = threadIdx.x >> 6;
  if (lane == 0) { sred[0][w] = r0; sred[1][w] = r1; }
  __syncthreads();
  if (threadIdx.x < 2) {
    float s = sred[threadIdx.x][0] + sred[threadIdx.x][1] +
              sred[threadIdx.x][2] + sred[threadIdx.x][3];
    atomicAdd(&ws[48 + threadIdx.x], s);
  }
}

__global__ void finalize_kernel(const float* __restrict__ ws, float* __restrict__ out) {
  // launched <<<1, 64>>>
  const int lane = threadIdx.x;
  float r = 0.f, t = 0.f, v = 0.f;
  if (lane < NSLICE) {
    r = ws[lane * 3 + 0];
    t = ws[lane * 3 + 1];
    v = ws[lane * 3 + 2];
  }
  r = waveReduceSum(r);
  t = waveReduceSum(t);
  v = waveReduceSum(v);
  if (lane == 0) {
    float nvis = ws[49];
    float recon = (nvis > 0.f) ? r / fmaxf(nvis, 1.f) : 0.f;
    float temporal = (v > 0.f) ? t / fmaxf(v, 1.f) : 0.f;
    float identity = ws[48] / (float)NN;

    float rl = recon, tl = temporal, il = identity;
    bool all_pos = (rl > 0.f) && (tl > 0.f) && (il > 0.f);
    float maxc = fmaxf(rl, fmaxf(tl, il));
    float target = maxc / 3.f;
    float thresh = 10.f * target;
    float rw = (all_pos && rl > thresh) ? 1.0f * target / fmaxf(rl, 1e-30f) : 1.0f;
    float tw = (all_pos && tl > thresh) ? 0.5f * target / fmaxf(tl, 1e-30f) : 0.5f;
    float iw = (all_pos && il > thresh) ? 0.1f * target / fmaxf(il, 1e-30f) : 0.1f;

    out[0] = rw * recon + tw * temporal + iw * identity;
    out[1] = recon;
    out[2] = temporal;
    out[3] = identity;
  }
}

extern "C" void kernel_launch(void* const* d_in, const int* in_sizes, int n_in,
                              void* d_out, int out_size, void* d_ws, size_t ws_size,
                              hipStream_t stream) {
  const float* pred = (const float*)d_in[0];
  const float* gt   = (const float*)d_in[1];
  const float* vis  = (const float*)d_in[2];
  float* out = (float*)d_out;
  float* ws  = (float*)d_ws;

  hipMemsetAsync(d_ws, 0, (WSBASE + (size_t)NSLICE * 13 * NN) * sizeof(float), stream);

  dim3 g1(NN / 256, BB, TT / CT);   // (8, 16, 8) = 1024 blocks
  stats_kernel<<<g1, 256, 0, stream>>>(pred, gt, vis, ws);
  identity_kernel<<<dim3(NN / 256), 256, 0, stream>>>(ws);
  finalize_kernel<<<1, 64, 0, stream>>>(ws, out);
}

// Round 2
// 256.271 us; speedup vs baseline: 1.1486x; 1.1486x over previous
//
#include <hip/hip_runtime.h>

#define BB 16
#define TT 256
#define NN 2048
#define TC 16            // t-chunk per block -> grid (8,16,16) = 2048 blocks
#define PD 4             // register prefetch depth (frames in flight)
#define NSLICE 16        // per-point partial slices (16 contenders each)
#define WSBASE 64        // scalar floats reserved at front of ws

// ws float layout:
//  [3*s + 0..2], s<16 : per-slice (recon_num, temporal_num, nvel) partials
//  [48] identity contrib sum   [49] num_visible   [50] ticket (int)
//  [WSBASE + (s*13 + k)*NN + n], s<16, k<13 : cnt, sp0..2, qp0..2, sg0..2, qg0..2

__device__ __forceinline__ float waveReduceSum(float v) {
#pragma unroll
  for (int o = 32; o > 0; o >>= 1) v += __shfl_down(v, o, 64);
  return v;
}

__global__ __launch_bounds__(256, 6) void stats_kernel(
    const float* __restrict__ pred, const float* __restrict__ gt,
    const float* __restrict__ vis, float* __restrict__ ws) {
  const int n  = blockIdx.x * 256 + threadIdx.x;
  const int b  = blockIdx.y;
  const int t0 = blockIdx.z * TC;

  const size_t frame0 = (size_t)(b * TT + t0) * NN + n;
  const float3* __restrict__ pp = (const float3*)pred + frame0;
  const float3* __restrict__ gp = (const float3*)gt + frame0;
  const float*  __restrict__ vp = vis + frame0;

  // boundary frame t0-1 (velocity state only); t0==0 loads frame 0 with mask 0
  float3 ppv, pgv;
  float mprev;
  {
    const long off = (t0 == 0) ? 0 : -(long)NN;
    ppv = pp[off];
    pgv = gp[off];
    float v = vp[off];
    mprev = (t0 != 0 && v > 0.5f) ? 1.f : 0.f;
  }

  // rotating register prefetch: PD frames in flight
  float3 P[PD], G[PD];
  float  Vv[PD];
#pragma unroll
  for (int d = 0; d < PD; ++d) {
    P[d]  = pp[(size_t)d * NN];
    G[d]  = gp[(size_t)d * NN];
    Vv[d] = vp[(size_t)d * NN];
  }

  float cnt = 0.f;
  float sp0 = 0, sp1 = 0, sp2 = 0, qp0 = 0, qp1 = 0, qp2 = 0;
  float sg0 = 0, sg1 = 0, sg2 = 0, qg0 = 0, qg1 = 0, qg2 = 0;
  float recon = 0, temporal = 0, nvel = 0;

#pragma unroll
  for (int i = 0; i < TC; ++i) {
    const int sl = i & (PD - 1);        // compile-time after full unroll
    float3 a = P[sl];
    float3 g = G[sl];
    float  v = Vv[sl];
    if (i + PD < TC) {                  // issue replacement load before compute
      P[sl]  = pp[(size_t)(i + PD) * NN];
      G[sl]  = gp[(size_t)(i + PD) * NN];
      Vv[sl] = vp[(size_t)(i + PD) * NN];
    }
    float m = (v > 0.5f) ? 1.f : 0.f;

    cnt += m;
    sp0 += m * a.x; sp1 += m * a.y; sp2 += m * a.z;
    qp0 += m * a.x * a.x; qp1 += m * a.y * a.y; qp2 += m * a.z * a.z;
    sg0 += m * g.x; sg1 += m * g.y; sg2 += m * g.z;
    qg0 += m * g.x * g.x; qg1 += m * g.y * g.y; qg2 += m * g.z * g.z;
    float d0 = a.x - g.x, d1 = a.y - g.y, d2 = a.z - g.z;
    recon += m * (d0 * d0 + d1 * d1 + 2.f * d2 * d2);

    float mv = m * mprev;
    float vx = (a.x - ppv.x) - (g.x - pgv.x);
    float vy = (a.y - ppv.y) - (g.y - pgv.y);
    float vz = (a.z - ppv.z) - (g.z - pgv.z);
    temporal += mv * (vx * vx + vy * vy + vz * vz);
    nvel += mv;

    ppv = a; pgv = g; mprev = m;
  }

  // per-point partials: 16 slices -> 16 contending blocks per address
  const int slice = (b + 2 * blockIdx.z) & (NSLICE - 1);
  float* pts = ws + WSBASE + (size_t)slice * 13 * NN;
  atomicAdd(&pts[0 * NN + n], cnt);
  atomicAdd(&pts[1 * NN + n], sp0);
  atomicAdd(&pts[2 * NN + n], sp1);
  atomicAdd(&pts[3 * NN + n], sp2);
  atomicAdd(&pts[4 * NN + n], qp0);
  atomicAdd(&pts[5 * NN + n], qp1);
  atomicAdd(&pts[6 * NN + n], qp2);
  atomicAdd(&pts[7 * NN + n], sg0);
  atomicAdd(&pts[8 * NN + n], sg1);
  atomicAdd(&pts[9 * NN + n], sg2);
  atomicAdd(&pts[10 * NN + n], qg0);
  atomicAdd(&pts[11 * NN + n], qg1);
  atomicAdd(&pts[12 * NN + n], qg2);

  // global scalars: block reduce, then one sliced atomic per scalar
  __shared__ float sred[3][4];
  float r0 = waveReduceSum(recon);
  float r1 = waveReduceSum(temporal);
  float r2 = waveReduceSum(nvel);
  int lane = threadIdx.x & 63, w = threadIdx.x >> 6;
  if (lane == 0) { sred[0][w] = r0; sred[1][w] = r1; sred[2][w] = r2; }
  __syncthreads();
  if (threadIdx.x < 3) {
    float s = sred[threadIdx.x][0] + sred[threadIdx.x][1] +
              sred[threadIdx.x][2] + sred[threadIdx.x][3];
    atomicAdd(&ws[slice * 3 + threadIdx.x], s);
  }
}

__global__ __launch_bounds__(256) void identity_kernel(float* __restrict__ ws,
                                                       float* __restrict__ out) {
  const int n = blockIdx.x * 256 + threadIdx.x;
  const float* base = ws + WSBASE;
  float st[13];
#pragma unroll
  for (int k = 0; k < 13; ++k) st[k] = 0.f;
#pragma unroll
  for (int s = 0; s < NSLICE; ++s) {
#pragma unroll
    for (int k = 0; k < 13; ++k) st[k] += base[(size_t)(s * 13 + k) * NN + n];
  }
  float c = st[0];
  float sp0 = st[1], sp1 = st[2], sp2 = st[3];
  float qp0 = st[4], qp1 = st[5], qp2 = st[6];
  float sg0 = st[7], sg1 = st[8], sg2 = st[9];
  float qg0 = st[10], qg1 = st[11], qg2 = st[12];

  float inv = 1.f / fmaxf(c, 1.f);
  float dv  = 1.f / fmaxf(c - 1.f, 1.f);
  float pv0 = (qp0 - sp0 * sp0 * inv) * dv;
  float pv1 = (qp1 - sp1 * sp1 * inv) * dv;
  float pv2 = (qp2 - sp2 * sp2 * inv) * dv;
  float gv0 = (qg0 - sg0 * sg0 * inv) * dv;
  float gv1 = (qg1 - sg1 * sg1 * inv) * dv;
  float gv2 = (qg2 - sg2 * sg2 * inv) * dv;

  float num = fabsf(pv0 - gv0) + fabsf(pv1 - gv1) + fabsf(pv2 - gv2);
  float den = gv0 + gv1 + gv2 + 1e-6f;
  float contrib = (c > 1.f) ? (num / den) : 0.f;

  __shared__ float sred[2][4];
  float r0 = waveReduceSum(contrib);
  float r1 = waveReduceSum(c);
  int lane = threadIdx.x & 63, w = threadIdx.x >> 6;
  if (lane == 0) { sred[0][w] = r0; sred[1][w] = r1; }
  __syncthreads();
  if (threadIdx.x < 2) {
    float s = sred[threadIdx.x][0] + sred[threadIdx.x][1] +
              sred[threadIdx.x][2] + sred[threadIdx.x][3];
    atomicAdd(&ws[48 + threadIdx.x], s);
  }

  // ---- fused finalize: last block (device-scope ticket) does the epilogue ----
  __threadfence();
  __shared__ int isLast;
  if (threadIdx.x == 0) {
    int old = atomicAdd((int*)(ws + 50), 1);
    isLast = (old == (int)gridDim.x - 1) ? 1 : 0;
  }
  __syncthreads();
  if (isLast && threadIdx.x < 64) {
    // coherent (device-scope) reads of the sliced scalar partials
    float r = 0.f, t = 0.f, v = 0.f;
    if (lane < NSLICE) {
      r = atomicAdd(&ws[lane * 3 + 0], 0.f);
      t = atomicAdd(&ws[lane * 3 + 1], 0.f);
      v = atomicAdd(&ws[lane * 3 + 2], 0.f);
    }
    r = waveReduceSum(r);
    t = waveReduceSum(t);
    v = waveReduceSum(v);
    if (lane == 0) {
      float idsum = atomicAdd(&ws[48], 0.f);
      float nvis  = atomicAdd(&ws[49], 0.f);
      float recon = (nvis > 0.f) ? r / fmaxf(nvis, 1.f) : 0.f;
      float temporal = (v > 0.f) ? t / fmaxf(v, 1.f) : 0.f;
      float identity = idsum / (float)NN;

      float rl = recon, tl = temporal, il = identity;
      bool all_pos = (rl > 0.f) && (tl > 0.f) && (il > 0.f);
      float maxc = fmaxf(rl, fmaxf(tl, il));
      float target = maxc / 3.f;
      float thresh = 10.f * target;
      float rw = (all_pos && rl > thresh) ? 1.0f * target / fmaxf(rl, 1e-30f) : 1.0f;
      float tw = (all_pos && tl > thresh) ? 0.5f * target / fmaxf(tl, 1e-30f) : 0.5f;
      float iw = (all_pos && il > thresh) ? 0.1f * target / fmaxf(il, 1e-30f) : 0.1f;

      out[0] = rw * recon + tw * temporal + iw * identity;
      out[1] = recon;
      out[2] = temporal;
      out[3] = identity;
    }
  }
}

extern "C" void kernel_launch(void* const* d_in, const int* in_sizes, int n_in,
                              void* d_out, int out_size, void* d_ws, size_t ws_size,
                              hipStream_t stream) {
  const float* pred = (const float*)d_in[0];
  const float* gt   = (const float*)d_in[1];
  const float* vis  = (const float*)d_in[2];
  float* out = (float*)d_out;
  float* ws  = (float*)d_ws;

  hipMemsetAsync(d_ws, 0, (WSBASE + (size_t)NSLICE * 13 * NN) * sizeof(float), stream);

  dim3 g1(NN / 256, BB, TT / TC);   // (8, 16, 16) = 2048 blocks
  stats_kernel<<<g1, 256, 0, stream>>>(pred, gt, vis, ws);
  identity_kernel<<<dim3(NN / 256), 256, 0, stream>>>(ws, out);
}